// Round 13
// baseline (498.036 us; speedup 1.0000x reference)
//
#include <hip/hip_runtime.h>

using u32 = unsigned int;
using s64 = long long;

// -------- int width detection --------
__global__ __launch_bounds__(64) void k_detect13(const u32* __restrict__ ei,
                                                 const u32* __restrict__ nt,
                                                 const u32* __restrict__ tp,
                                                 u32* __restrict__ flags) {
    if (blockIdx.x != 0 || threadIdx.x != 0) return;
    bool e64 = true, n64 = true, t64 = true;
    for (int k = 0; k < 64; ++k) {
        if (ei[2 * k + 1] != 0u) e64 = false;
        if (nt[2 * k + 1] != 0u) n64 = false;
        if (tp[2 * k + 1] != 0u) t64 = false;
    }
    flags[0] = e64 ? 1u : 0u;
    flags[1] = n64 ? 1u : 0u;
    flags[2] = t64 ? 1u : 0u;
}

__global__ __launch_bounds__(256) void k_cvt13(const void* __restrict__ src,
                                               int* __restrict__ dst, long long n,
                                               const u32* __restrict__ flags, int fidx) {
    long long i = (long long)blockIdx.x * 256 + threadIdx.x;
    if (i >= n) return;
    dst[i] = flags[fidx] ? (int)((const s64*)src)[i] : ((const int*)src)[i];
}

__global__ __launch_bounds__(256) void kz_i(int* __restrict__ p, int n) {
    int i = blockIdx.x * 256 + threadIdx.x;
    if (i < n) p[i] = 0;
}

// ---------------- counting sort of edges by col ----------------
__global__ __launch_bounds__(256) void k_hist(const int* __restrict__ ei, int E,
                                              int* __restrict__ cnt) {
    int e = blockIdx.x * 256 + threadIdx.x;
    if (e < E) atomicAdd(&cnt[ei[E + e]], 1);
}

__global__ __launch_bounds__(1024) void k_scan(const int* __restrict__ cnt,
                                               int* __restrict__ offA, int N) {
    __shared__ int part[1024];
    int t = threadIdx.x;
    int C = (N + 1023) >> 10;
    int beg = t * C, end = beg + C; if (end > N) end = N;
    int s = 0;
    for (int k = beg; k < end; ++k) s += cnt[k];
    part[t] = s; __syncthreads();
    for (int o = 1; o < 1024; o <<= 1) {
        int v = (t >= o) ? part[t - o] : 0;
        __syncthreads();
        part[t] += v;
        __syncthreads();
    }
    int base = (t == 0) ? 0 : part[t - 1];
    for (int k = beg; k < end; ++k) { offA[k] = base; base += cnt[k]; }
    if (t == 1023) offA[N] = part[1023];
}

__global__ __launch_bounds__(256) void k_scatter(const int* __restrict__ ei, int E,
                                                 const int* __restrict__ offA,
                                                 int* __restrict__ cur,
                                                 int* __restrict__ srow) {
    int e = blockIdx.x * 256 + threadIdx.x;
    if (e >= E) return;
    int col = ei[E + e];
    int p = offA[col] + atomicAdd(&cur[col], 1);
    srow[p] = ei[e];
}

// ---------------- counting sort of nodes by type ----------------
__global__ __launch_bounds__(256) void k_thist(const int* __restrict__ nt, int N,
                                               int* __restrict__ tcnt) {
    __shared__ int lc[6];
    if (threadIdx.x < 6) lc[threadIdx.x] = 0;
    __syncthreads();
    int i = blockIdx.x * 256 + threadIdx.x;
    if (i < N) {
        int t = nt[i]; t = (t < 0 || t > 5) ? 0 : t;
        atomicAdd(&lc[t], 1);
    }
    __syncthreads();
    if (threadIdx.x < 6 && lc[threadIdx.x] > 0) atomicAdd(&tcnt[threadIdx.x], lc[threadIdx.x]);
}

__global__ __launch_bounds__(64) void k_tscan(const int* __restrict__ tcnt,
                                              int* __restrict__ toff) {
    if (threadIdx.x != 0 || blockIdx.x != 0) return;
    int s = 0;
    for (int t = 0; t < 6; ++t) { toff[t] = s; s += tcnt[t]; }
    toff[6] = s;
}

__global__ __launch_bounds__(256) void k_tscatter(const int* __restrict__ nt, int N,
                                                  const int* __restrict__ toff,
                                                  int* __restrict__ tcur,
                                                  int* __restrict__ perm) {
    __shared__ int lc[6], gb[6];
    if (threadIdx.x < 6) lc[threadIdx.x] = 0;
    __syncthreads();
    int i = blockIdx.x * 256 + threadIdx.x;
    int t = 0, lr = 0;
    if (i < N) {
        t = nt[i]; t = (t < 0 || t > 5) ? 0 : t;
        lr = atomicAdd(&lc[t], 1);
    }
    __syncthreads();
    if (threadIdx.x < 6 && lc[threadIdx.x] > 0)
        gb[threadIdx.x] = atomicAdd(&tcur[threadIdx.x], lc[threadIdx.x]);
    __syncthreads();
    if (i < N) perm[toff[t] + gb[t] + lr] = i;
}

__device__ __forceinline__ float2 ld2(const float* p) { return *(const float2*)p; }
__device__ __forceinline__ void st2(float* p, float2 v) { *(float2*)p = v; }
__device__ __forceinline__ float4 ld4(const float* p) { return *(const float4*)p; }
__device__ __forceinline__ void st4(float* p, float4 v) { *(float4*)p = v; }
__device__ __forceinline__ void fma4(float4& a, float s, float4 w) {
    a.x = fmaf(s, w.x, a.x); a.y = fmaf(s, w.y, a.y);
    a.z = fmaf(s, w.z, a.z); a.w = fmaf(s, w.w, a.w);
}

__device__ __forceinline__ float redrow(float s) {
#pragma unroll
    for (int o = 1; o < 32; o <<= 1) s += __shfl_xor(s, o);
    return s;
}

// ======================= staged matmul (R7-proven; unroll-4 inner) =======================
// xs 16KB + wl 32KB = 48KB -> 3 blocks/CU.

__device__ __forceinline__ void stage_half(float* wl, const float* __restrict__ Wg,
                                           int half) {
    int t = threadIdx.x;
    const float* src = Wg + half * 8192;
#pragma unroll
    for (int i = 0; i < 8; ++i) {
        int idx = (t + i * 256) * 4;
        st4(wl + idx, ld4(src + idx));
    }
}

__device__ __forceinline__ void mm_half(float4 (&acc)[4], const float* xs,
                                        const float* wl, int tn, int tc, int k4base) {
#pragma unroll 4
    for (int k4 = 0; k4 < 16; ++k4) {
        int r = k4 * 4;
        float4 w0 = ld4(wl + (r + 0) * 128 + tc * 4);
        float4 w1 = ld4(wl + (r + 1) * 128 + tc * 4);
        float4 w2 = ld4(wl + (r + 2) * 128 + tc * 4);
        float4 w3 = ld4(wl + (r + 3) * 128 + tc * 4);
#pragma unroll
        for (int j = 0; j < 4; ++j) {
            float4 xv = ld4(xs + (tn * 4 + j) * 128 + (k4base + k4) * 4);
            fma4(acc[j], xv.x, w0); fma4(acc[j], xv.y, w1);
            fma4(acc[j], xv.z, w2); fma4(acc[j], xv.w, w3);
        }
    }
}

__device__ __forceinline__ void mmS(float4 (&acc)[4], const float* xs, float* wl,
                                    const float* __restrict__ Wg, int tn, int tc) {
    __syncthreads();
    stage_half(wl, Wg, 0);
    __syncthreads();
    mm_half(acc, xs, wl, tn, tc, 0);
    __syncthreads();
    stage_half(wl, Wg, 1);
    __syncthreads();
    mm_half(acc, xs, wl, tn, tc, 16);
}

__device__ __forceinline__ float4 lnrow(float4 v, const float* g, const float* b, int tc) {
    float m = redrow(v.x + v.y + v.z + v.w) * 0.0078125f;
    float4 d = make_float4(v.x - m, v.y - m, v.z - m, v.w - m);
    float var = redrow(d.x * d.x + d.y * d.y + d.z * d.z + d.w * d.w) * 0.0078125f;
    float r = rsqrtf(var + 1e-5f);
    float4 gg = ld4(g + tc * 4), bb = ld4(b + tc * 4);
    return make_float4(d.x * r * gg.x + bb.x, d.y * r * gg.y + bb.y,
                       d.z * r * gg.z + bb.z, d.w * r * gg.w + bb.w);
}

__device__ __forceinline__ void stage32(float* xs, const float* src, int i0, int N) {
    int t = threadIdx.x;
#pragma unroll
    for (int ii = 0; ii < 4; ++ii) {
        int idx = t + ii * 256;
        int r = idx >> 5, c = idx & 31;
        int node = i0 + r; if (node >= N) node = N - 1;
        st4(xs + r * 128 + c * 4, ld4(src + (size_t)node * 128 + c * 4));
    }
}

__device__ __forceinline__ void xstore(float* xs, const float4 (&v)[4], int tn, int tc) {
#pragma unroll
    for (int j = 0; j < 4; ++j) st4(xs + (tn * 4 + j) * 128 + tc * 4, v[j]);
}

// ============ MEGA1: qkv | hgcn+pre_gcn | pre_tmp (role = blockIdx%3) ============
__global__ __launch_bounds__(256) void k_mega1(
        const float* __restrict__ x,
        const float* __restrict__ Wq, const float* __restrict__ Wk,
        const float* __restrict__ Wv, float* __restrict__ big,
        const int* __restrict__ nt, const int* __restrict__ perm,
        const float* __restrict__ Wt, const float* __restrict__ bt,
        float* __restrict__ h_gcn,
        const float* __restrict__ mW1, const float* __restrict__ mb1,
        float* __restrict__ Pa_g, float* __restrict__ Pb_g,
        const float* __restrict__ emb, const int* __restrict__ tpos,
        const float* __restrict__ tW1, const float* __restrict__ tb1,
        float* __restrict__ Pa_t, float* __restrict__ Pb_t,
        int N) {
    __shared__ float xs[32 * 128];
    __shared__ float wl[64 * 128];
    int role = blockIdx.x % 3;
    int bid = blockIdx.x / 3;
    int t = threadIdx.x, tn = t >> 5, tc = t & 31;
    int i0 = bid * 32;

    if (role == 0) {
        stage32(xs, x, i0, N);
        float4 acc[4];
        const float* Ws[3] = {Wq, Wk, Wv};
#pragma unroll
        for (int m = 0; m < 3; ++m) {
#pragma unroll
            for (int j = 0; j < 4; ++j) acc[j] = make_float4(0.f, 0.f, 0.f, 0.f);
            mmS(acc, xs, wl, Ws[m], tn, tc);
#pragma unroll
            for (int j = 0; j < 4; ++j) {
                int node = i0 + tn * 4 + j;
                if (node < N) st4(big + (size_t)node * 384 + m * 128 + tc * 4, acc[j]);
            }
        }
    } else if (role == 1) {
        // hgcn + pre_gcn chained
#pragma unroll
        for (int ii = 0; ii < 4; ++ii) {
            int idx = t + ii * 256;
            int r = idx >> 5, c = idx & 31;
            int q = i0 + r; if (q >= N) q = N - 1;
            int node = perm[q];
            st4(xs + r * 128 + c * 4, ld4(x + (size_t)node * 128 + c * 4));
        }
        int qa = i0; if (qa >= N) qa = N - 1;
        int qb = i0 + 31; if (qb >= N) qb = N - 1;
        int t0 = nt[perm[qa]]; t0 = (t0 < 0 || t0 > 5) ? 0 : t0;
        int t1 = nt[perm[qb]]; t1 = (t1 < 0 || t1 > 5) ? 0 : t1;
        float4 acc[4];
        if (t0 == t1) {
#pragma unroll
            for (int j = 0; j < 4; ++j) acc[j] = ld4(bt + t0 * 128 + tc * 4);
            mmS(acc, xs, wl, Wt + (size_t)t0 * 16384, tn, tc);
        } else {
            __syncthreads();
#pragma unroll
            for (int j = 0; j < 4; ++j) {
                int q = i0 + tn * 4 + j; if (q >= N) q = N - 1;
                int tt = nt[perm[q]]; tt = (tt < 0 || tt > 5) ? 0 : tt;
                const float* W = Wt + (size_t)tt * 16384;
                float4 a = ld4(bt + tt * 128 + tc * 4);
#pragma unroll 2
                for (int k4 = 0; k4 < 32; ++k4) {
                    float4 xv = ld4(xs + (tn * 4 + j) * 128 + k4 * 4);
                    float4 w0 = ld4(W + (size_t)(k4 * 4 + 0) * 128 + tc * 4);
                    float4 w1 = ld4(W + (size_t)(k4 * 4 + 1) * 128 + tc * 4);
                    float4 w2 = ld4(W + (size_t)(k4 * 4 + 2) * 128 + tc * 4);
                    float4 w3 = ld4(W + (size_t)(k4 * 4 + 3) * 128 + tc * 4);
                    fma4(a, xv.x, w0); fma4(a, xv.y, w1);
                    fma4(a, xv.z, w2); fma4(a, xv.w, w3);
                }
                acc[j] = a;
            }
        }
#pragma unroll
        for (int j = 0; j < 4; ++j) {
            int q = i0 + tn * 4 + j;
            if (q < N) st4(h_gcn + (size_t)perm[q] * 128 + tc * 4, acc[j]);
        }
        __syncthreads();
        xstore(xs, acc, tn, tc);
        float4 pa[4];
#pragma unroll
        for (int j = 0; j < 4; ++j) pa[j] = make_float4(0.f, 0.f, 0.f, 0.f);
        mmS(pa, xs, wl, mW1, tn, tc);
#pragma unroll
        for (int j = 0; j < 4; ++j) {
            int q = i0 + tn * 4 + j;
            if (q < N) st4(Pa_g + (size_t)perm[q] * 128 + tc * 4, pa[j]);
        }
        float4 b14 = ld4(mb1 + tc * 4);
        float4 pb[4];
#pragma unroll
        for (int j = 0; j < 4; ++j) pb[j] = b14;
        mmS(pb, xs, wl, mW1 + (size_t)128 * 128, tn, tc);
#pragma unroll
        for (int j = 0; j < 4; ++j) {
            int q = i0 + tn * 4 + j;
            if (q < N) st4(Pb_g + (size_t)perm[q] * 128 + tc * 4, pb[j]);
        }
    } else {
        // pre_tmp (h = x + emb inline)
#pragma unroll
        for (int ii = 0; ii < 4; ++ii) {
            int idx = t + ii * 256;
            int r = idx >> 5, c = idx & 31;
            int node = i0 + r; if (node >= N) node = N - 1;
            float4 v = ld4(x + (size_t)node * 128 + c * 4);
            int tp = tpos[node]; tp = tp < 0 ? 0 : (tp > 49 ? 49 : tp);
            float4 e = ld4(emb + tp * 128 + c * 4);
            v.x += e.x; v.y += e.y; v.z += e.z; v.w += e.w;
            st4(xs + r * 128 + c * 4, v);
        }
        float4 acc[4];
#pragma unroll
        for (int j = 0; j < 4; ++j) acc[j] = make_float4(0.f, 0.f, 0.f, 0.f);
        mmS(acc, xs, wl, tW1, tn, tc);
#pragma unroll
        for (int j = 0; j < 4; ++j) {
            int node = i0 + tn * 4 + j;
            if (node < N) st4(Pa_t + (size_t)node * 128 + tc * 4, acc[j]);
        }
        float4 b14 = ld4(tb1 + tc * 4);
#pragma unroll
        for (int j = 0; j < 4; ++j) acc[j] = b14;
        mmS(acc, xs, wl, tW1 + (size_t)128 * 128, tn, tc);
#pragma unroll
        for (int j = 0; j < 4; ++j) {
            int node = i0 + tn * 4 + j;
            if (node < N) st4(Pb_t + (size_t)node * 128 + tc * 4, acc[j]);
        }
    }
}

// rsum body (s aliases Pb: pb read before s written)
__device__ __forceinline__ void rsum_body(const float* __restrict__ Pa,
                                          float* __restrict__ Pb,
                                          const int* __restrict__ srow,
                                          const int* __restrict__ offA, int N, int cb) {
    int l = threadIdx.x & 63;
    int col = cb * 4 + (threadIdx.x >> 6);
    if (col >= N) return;
    float2 pb = ld2(Pb + (size_t)col * 128 + 2 * l);
    float ax = 0.f, ay = 0.f;
    int p = offA[col], pe = offA[col + 1];
    for (; p + 4 <= pe; p += 4) {
        int r0 = srow[p], r1 = srow[p + 1], r2 = srow[p + 2], r3 = srow[p + 3];
        float2 a0 = ld2(Pa + (size_t)r0 * 128 + 2 * l);
        float2 a1 = ld2(Pa + (size_t)r1 * 128 + 2 * l);
        float2 a2 = ld2(Pa + (size_t)r2 * 128 + 2 * l);
        float2 a3 = ld2(Pa + (size_t)r3 * 128 + 2 * l);
        ax += fmaxf(a0.x + pb.x, 0.f) + fmaxf(a1.x + pb.x, 0.f)
            + fmaxf(a2.x + pb.x, 0.f) + fmaxf(a3.x + pb.x, 0.f);
        ay += fmaxf(a0.y + pb.y, 0.f) + fmaxf(a1.y + pb.y, 0.f)
            + fmaxf(a2.y + pb.y, 0.f) + fmaxf(a3.y + pb.y, 0.f);
    }
    for (; p < pe; ++p) {
        int r = srow[p];
        float2 a = ld2(Pa + (size_t)r * 128 + 2 * l);
        ax += fmaxf(a.x + pb.x, 0.f);
        ay += fmaxf(a.y + pb.y, 0.f);
    }
    st2(Pb + (size_t)col * 128 + 2 * l, make_float2(ax, ay));
}

// ============ MEGA2: fused GAT softmax+WV | rsum_gcn | rsum_tmp ============
__global__ __launch_bounds__(256) void k_mega2(
        const float* __restrict__ big,
        const float* __restrict__ Pa_g, float* __restrict__ Pb_g,
        const float* __restrict__ Pa_t, float* __restrict__ Pb_t,
        const int* __restrict__ srow, const int* __restrict__ offA,
        float* __restrict__ agg, int N) {
    int role = blockIdx.x % 3;
    int cb = blockIdx.x / 3;
    if (role == 1) { rsum_body(Pa_g, Pb_g, srow, offA, N, cb); return; }
    if (role == 2) { rsum_body(Pa_t, Pb_t, srow, offA, N, cb); return; }
    // ---- fused GAT ----
    int l = threadIdx.x & 63;
    int col = cb * 4 + (threadIdx.x >> 6);
    if (col >= N) return;
    float2 kc = ld2(big + (size_t)col * 384 + 128 + 2 * l);
    float ax = 0.f, ay = 0.f, den = 0.f;
    int p = offA[col], pe = offA[col + 1];
    for (; p + 2 <= pe; p += 2) {
        int r0 = srow[p], r1 = srow[p + 1];
        float2 q0 = ld2(big + (size_t)r0 * 384 + 2 * l);
        float2 v0 = ld2(big + (size_t)r0 * 384 + 256 + 2 * l);
        float2 q1 = ld2(big + (size_t)r1 * 384 + 2 * l);
        float2 v1 = ld2(big + (size_t)r1 * 384 + 256 + 2 * l);
        float pt0 = q0.x * kc.x + q0.y * kc.y;
        float pt1 = q1.x * kc.x + q1.y * kc.y;
        pt0 += __shfl_xor(pt0, 1); pt1 += __shfl_xor(pt1, 1);
        pt0 += __shfl_xor(pt0, 2); pt1 += __shfl_xor(pt1, 2);
        pt0 += __shfl_xor(pt0, 4); pt1 += __shfl_xor(pt1, 4);
        float s0 = pt0 * 0.25f; s0 = s0 > 0.f ? s0 : 0.2f * s0;
        float s1 = pt1 * 0.25f; s1 = s1 > 0.f ? s1 : 0.2f * s1;
        float e0 = expf(s0), e1 = expf(s1);
        den += e0 + e1;
        ax = fmaf(e0, v0.x, ax); ay = fmaf(e0, v0.y, ay);
        ax = fmaf(e1, v1.x, ax); ay = fmaf(e1, v1.y, ay);
    }
    for (; p < pe; ++p) {
        int r = srow[p];
        float2 q0 = ld2(big + (size_t)r * 384 + 2 * l);
        float2 v0 = ld2(big + (size_t)r * 384 + 256 + 2 * l);
        float pt = q0.x * kc.x + q0.y * kc.y;
        pt += __shfl_xor(pt, 1);
        pt += __shfl_xor(pt, 2);
        pt += __shfl_xor(pt, 4);
        float s = pt * 0.25f; s = s > 0.f ? s : 0.2f * s;
        float e = expf(s);
        den += e;
        ax = fmaf(e, v0.x, ax); ay = fmaf(e, v0.y, ay);
    }
    float ism = den != 0.f ? 1.f / den : 0.f;
    st2(agg + (size_t)col * 128 + 2 * l, make_float2(ax * ism, ay * ism));
}

// ============ MEGA3: epilogues + fusW partials (role = blockIdx%3) ============
__global__ __launch_bounds__(256) void k_mega3(
        const float* __restrict__ x,
        const float* __restrict__ agg,
        const float* __restrict__ gWo, const float* __restrict__ gbo,
        const float* __restrict__ gg, const float* __restrict__ gb,
        float* __restrict__ p0,
        const float* __restrict__ h_gcn, const float* __restrict__ s_gcn,
        const int* __restrict__ offA,
        const float* __restrict__ W2, const float* __restrict__ b2,
        const float* __restrict__ aW1, const float* __restrict__ ab1,
        const float* __restrict__ aW2, const float* __restrict__ ab2,
        const float* __restrict__ cWo, const float* __restrict__ cbo,
        const float* __restrict__ cg, const float* __restrict__ cb,
        float* __restrict__ p1,
        const float* __restrict__ emb, const int* __restrict__ tpos,
        const float* __restrict__ s_tmp,
        const float* __restrict__ tW2, const float* __restrict__ tb2,
        const float* __restrict__ tWo, const float* __restrict__ tbo,
        const float* __restrict__ tg, const float* __restrict__ tb,
        float* __restrict__ p2,
        const float* __restrict__ fusW, const float* __restrict__ fus_b,
        int N) {
    __shared__ float xs[32 * 128];
    __shared__ float wl[64 * 128];
    int role = blockIdx.x % 3;
    int bid = blockIdx.x / 3;
    int t = threadIdx.x, tn = t >> 5, tc = t & 31;
    int i0 = bid * 32;
    int node[4];
#pragma unroll
    for (int j = 0; j < 4; ++j) {
        node[j] = i0 + tn * 4 + j; if (node[j] >= N) node[j] = N - 1;
    }
    float4 o[4];

    if (role == 0) {
        // ep_gat: o = LN(agg@Wo + bo + x); p0 = fus_b + o@fusW0
        stage32(xs, agg, i0, N);
        float4 acc[4];
        float4 bo4 = ld4(gbo + tc * 4);
#pragma unroll
        for (int j = 0; j < 4; ++j) acc[j] = bo4;
        mmS(acc, xs, wl, gWo, tn, tc);
#pragma unroll
        for (int j = 0; j < 4; ++j) {
            float4 xr = ld4(x + (size_t)node[j] * 128 + tc * 4);
            float4 v = make_float4(acc[j].x + xr.x, acc[j].y + xr.y,
                                   acc[j].z + xr.z, acc[j].w + xr.w);
            o[j] = lnrow(v, gg, gb, tc);
        }
        __syncthreads();
        xstore(xs, o, tn, tc);
        float4 fb4 = ld4(fus_b + tc * 4);
#pragma unroll
        for (int j = 0; j < 4; ++j) acc[j] = fb4;
        mmS(acc, xs, wl, fusW, tn, tc);
#pragma unroll
        for (int j = 0; j < 4; ++j) {
            int q = i0 + tn * 4 + j;
            if (q < N) st4(p0 + (size_t)q * 128 + tc * 4, acc[j]);
        }
    } else if (role == 1) {
        // ep_gcn
        stage32(xs, s_gcn, i0, N);
        float4 acc[4];
        float4 b24 = ld4(b2 + tc * 4);
#pragma unroll
        for (int j = 0; j < 4; ++j) {
            float deg = (float)(offA[node[j] + 1] - offA[node[j]]);
            acc[j] = make_float4(deg * b24.x, deg * b24.y, deg * b24.z, deg * b24.w);
        }
        mmS(acc, xs, wl, W2, tn, tc);
        __syncthreads();
        xstore(xs, acc, tn, tc);
        float4 u[4];
        float4 a14 = ld4(ab1 + tc * 4);
#pragma unroll
        for (int j = 0; j < 4; ++j) u[j] = a14;
        mmS(u, xs, wl, aW1, tn, tc);
#pragma unroll
        for (int j = 0; j < 4; ++j) {
            u[j].x = fmaxf(u[j].x, 0.f); u[j].y = fmaxf(u[j].y, 0.f);
            u[j].z = fmaxf(u[j].z, 0.f); u[j].w = fmaxf(u[j].w, 0.f);
        }
        __syncthreads();
        xstore(xs, u, tn, tc);
        float4 z3[4];
        float4 a24 = ld4(ab2 + tc * 4);
#pragma unroll
        for (int j = 0; j < 4; ++j) z3[j] = a24;
        mmS(z3, xs, wl, aW2, tn, tc);
#pragma unroll
        for (int j = 0; j < 4; ++j) {
            float4 hg = ld4(h_gcn + (size_t)node[j] * 128 + tc * 4);
            z3[j].x += hg.x; z3[j].y += hg.y; z3[j].z += hg.z; z3[j].w += hg.w;
        }
        __syncthreads();
        xstore(xs, z3, tn, tc);
        float4 d[4];
        float4 bo4 = ld4(cbo + tc * 4);
#pragma unroll
        for (int j = 0; j < 4; ++j) d[j] = bo4;
        mmS(d, xs, wl, cWo, tn, tc);
#pragma unroll
        for (int j = 0; j < 4; ++j) {
            float4 xr = ld4(x + (size_t)node[j] * 128 + tc * 4);
            float4 v = make_float4(d[j].x + xr.x, d[j].y + xr.y,
                                   d[j].z + xr.z, d[j].w + xr.w);
            o[j] = lnrow(v, cg, cb, tc);
        }
        __syncthreads();
        xstore(xs, o, tn, tc);
#pragma unroll
        for (int j = 0; j < 4; ++j) d[j] = make_float4(0.f, 0.f, 0.f, 0.f);
        mmS(d, xs, wl, fusW + (size_t)128 * 128, tn, tc);
#pragma unroll
        for (int j = 0; j < 4; ++j) {
            int q = i0 + tn * 4 + j;
            if (q < N) st4(p1 + (size_t)q * 128 + tc * 4, d[j]);
        }
    } else {
        // ep_tmp
        stage32(xs, s_tmp, i0, N);
        float4 acc[4];
        float4 b24 = ld4(tb2 + tc * 4);
#pragma unroll
        for (int j = 0; j < 4; ++j) {
            float deg = (float)(offA[node[j] + 1] - offA[node[j]]);
            acc[j] = make_float4(deg * b24.x, deg * b24.y, deg * b24.z, deg * b24.w);
        }
        mmS(acc, xs, wl, tW2, tn, tc);
#pragma unroll
        for (int j = 0; j < 4; ++j) {
            int tp = tpos[node[j]]; tp = tp < 0 ? 0 : (tp > 49 ? 49 : tp);
            float4 xr = ld4(x + (size_t)node[j] * 128 + tc * 4);
            float4 e = ld4(emb + tp * 128 + tc * 4);
            acc[j].x += xr.x + e.x; acc[j].y += xr.y + e.y;
            acc[j].z += xr.z + e.z; acc[j].w += xr.w + e.w;
        }
        __syncthreads();
        xstore(xs, acc, tn, tc);
        float4 d[4];
        float4 bo4 = ld4(tbo + tc * 4);
#pragma unroll
        for (int j = 0; j < 4; ++j) d[j] = bo4;
        mmS(d, xs, wl, tWo, tn, tc);
#pragma unroll
        for (int j = 0; j < 4; ++j) o[j] = lnrow(d[j], tg, tb, tc);
        __syncthreads();
        xstore(xs, o, tn, tc);
#pragma unroll
        for (int j = 0; j < 4; ++j) d[j] = make_float4(0.f, 0.f, 0.f, 0.f);
        mmS(d, xs, wl, fusW + (size_t)256 * 128, tn, tc);
#pragma unroll
        for (int j = 0; j < 4; ++j) {
            int q = i0 + tn * 4 + j;
            if (q < N) st4(p2 + (size_t)q * 128 + tc * 4, d[j]);
        }
    }
}

// ============ FINAL: out = LN(p0 + p1 + p2) (elementwise rows) ============
__global__ __launch_bounds__(256) void k_finE(
        const float* __restrict__ p0, const float* __restrict__ p1,
        const float* __restrict__ p2,
        const float* __restrict__ fg, const float* __restrict__ fbe,
        float* __restrict__ out, int N) {
    int t = threadIdx.x, tn = t >> 5, tc = t & 31;
    int i0 = blockIdx.x * 32;
#pragma unroll
    for (int j = 0; j < 4; ++j) {
        int node = i0 + tn * 4 + j;
        int nc = node < N ? node : N - 1;
        float4 a = ld4(p0 + (size_t)nc * 128 + tc * 4);
        float4 b = ld4(p1 + (size_t)nc * 128 + tc * 4);
        float4 c = ld4(p2 + (size_t)nc * 128 + tc * 4);
        float4 v = make_float4(a.x + b.x + c.x, a.y + b.y + c.y,
                               a.z + b.z + c.z, a.w + b.w + c.w);
        float4 o = lnrow(v, fg, fbe, tc);
        if (node < N) st4(out + (size_t)node * 128 + tc * 4, o);
    }
}

extern "C" void kernel_launch(void* const* d_in, const int* in_sizes, int n_in, void* d_out,
                              int out_size, void* d_ws, size_t ws_size, hipStream_t stream) {
    (void)n_in; (void)out_size; (void)ws_size;
    const float* x = (const float*)d_in[0];
    const float* gat_Wq = (const float*)d_in[4];
    const float* gat_Wk = (const float*)d_in[5];
    const float* gat_Wv = (const float*)d_in[6];
    const float* gat_Wo = (const float*)d_in[7];
    const float* gat_bo = (const float*)d_in[8];
    const float* gat_g = (const float*)d_in[9];
    const float* gat_b = (const float*)d_in[10];
    const float* gcn_Wt = (const float*)d_in[11];
    const float* gcn_bt = (const float*)d_in[12];
    const float* gcn_mW1 = (const float*)d_in[13];
    const float* gcn_mb1 = (const float*)d_in[14];
    const float* gcn_mW2 = (const float*)d_in[15];
    const float* gcn_mb2 = (const float*)d_in[16];
    const float* gcn_aW1 = (const float*)d_in[17];
    const float* gcn_ab1 = (const float*)d_in[18];
    const float* gcn_aW2 = (const float*)d_in[19];
    const float* gcn_ab2 = (const float*)d_in[20];
    const float* gcn_Wo = (const float*)d_in[21];
    const float* gcn_bo = (const float*)d_in[22];
    const float* gcn_g = (const float*)d_in[23];
    const float* gcn_b = (const float*)d_in[24];
    const float* tmp_emb = (const float*)d_in[25];
    const float* tmp_W1 = (const float*)d_in[26];
    const float* tmp_b1 = (const float*)d_in[27];
    const float* tmp_W2 = (const float*)d_in[28];
    const float* tmp_b2 = (const float*)d_in[29];
    const float* tmp_Wo = (const float*)d_in[30];
    const float* tmp_bo = (const float*)d_in[31];
    const float* tmp_g = (const float*)d_in[32];
    const float* tmp_b = (const float*)d_in[33];
    const float* fus_W = (const float*)d_in[34];
    const float* fus_b = (const float*)d_in[35];
    const float* fus_g = (const float*)d_in[36];
    const float* fus_be = (const float*)d_in[37];

    int N = in_sizes[0] / 128;
    int E = in_sizes[1] / 2;

    // ---- workspace layout ----
    float* ws = (float*)d_ws;
    float* big = ws;                          // [0,384N): QKV; p0/p1/p2 after mega3
    float* p0 = ws;
    float* p1 = ws + (size_t)128 * N;
    float* p2 = ws + (size_t)256 * N;
    float* h_gcn = ws + (size_t)384 * N;      // [384N,512N)
    float* Pa_g = ws + (size_t)512 * N;       // [512N,640N)
    float* Pb_g = ws + (size_t)640 * N;       // s_gcn in-place
    float* Pa_t = ws + (size_t)768 * N;       // [768N,896N)
    float* Pb_t = ws + (size_t)896 * N;       // s_tmp in-place
    float* agg = ws + (size_t)1024 * N;       // [1024N,1152N)
    u32* flags = (u32*)(ws + (size_t)1152 * N);
    int* ei32 = (int*)(flags + 16);
    int* nt32 = ei32 + (size_t)2 * E;
    int* tp32 = nt32 + N;
    int* offA = tp32 + N;                     // N+1
    int* cur = offA + (N + 1);                // N
    int* srow = cur + N;                      // E
    int* tcnt = srow + E;                     // 6
    int* toff = tcnt + 6;                     // 7
    int* tcur = toff + 7;                     // 6
    int* perm = cur;                          // alias after col-scatter

    // ---- index canonicalization ----
    k_detect13<<<1, 64, 0, stream>>>((const u32*)d_in[1], (const u32*)d_in[2],
                                     (const u32*)d_in[3], flags);
    long long nEI = (long long)2 * E;
    k_cvt13<<<(int)((nEI + 255) / 256), 256, 0, stream>>>(d_in[1], ei32, nEI, flags, 0);
    k_cvt13<<<(N + 255) / 256, 256, 0, stream>>>(d_in[2], nt32, N, flags, 1);
    k_cvt13<<<(N + 255) / 256, 256, 0, stream>>>(d_in[3], tp32, N, flags, 2);

    int gE = (E + 255) / 256;
    int gN = (N + 255) / 256;
    int gT = (N + 31) / 32;
    int gC = (N + 3) / 4;

    // ---- counting sort of edges by col ----
    kz_i<<<gN, 256, 0, stream>>>(cur, N);
    k_hist<<<gE, 256, 0, stream>>>(ei32, E, cur);
    k_scan<<<1, 1024, 0, stream>>>(cur, offA, N);
    kz_i<<<gN, 256, 0, stream>>>(cur, N);
    k_scatter<<<gE, 256, 0, stream>>>(ei32, E, offA, cur, srow);

    // ---- counting sort of nodes by type ----
    kz_i<<<1, 32, 0, stream>>>(tcnt, 19);
    k_thist<<<gN, 256, 0, stream>>>(nt32, N, tcnt);
    k_tscan<<<1, 64, 0, stream>>>(tcnt, toff);
    k_tscatter<<<gN, 256, 0, stream>>>(nt32, N, toff, tcur, perm);

    // ---- MEGA1: qkv | hgcn+pre_gcn | pre_tmp ----
    k_mega1<<<3 * gT, 256, 0, stream>>>(x, gat_Wq, gat_Wk, gat_Wv, big,
                                        nt32, perm, gcn_Wt, gcn_bt, h_gcn,
                                        gcn_mW1, gcn_mb1, Pa_g, Pb_g,
                                        tmp_emb, tp32, tmp_W1, tmp_b1, Pa_t, Pb_t, N);

    // ---- MEGA2: fused GAT | rsum_gcn | rsum_tmp ----
    k_mega2<<<3 * gC, 256, 0, stream>>>(big, Pa_g, Pb_g, Pa_t, Pb_t,
                                        srow, offA, agg, N);

    // ---- MEGA3: epilogues + fusW partials ----
    k_mega3<<<3 * gT, 256, 0, stream>>>(x, agg, gat_Wo, gat_bo, gat_g, gat_b, p0,
                                        h_gcn, Pb_g, offA, gcn_mW2, gcn_mb2,
                                        gcn_aW1, gcn_ab1, gcn_aW2, gcn_ab2,
                                        gcn_Wo, gcn_bo, gcn_g, gcn_b, p1,
                                        tmp_emb, tp32, Pb_t, tmp_W2, tmp_b2,
                                        tmp_Wo, tmp_bo, tmp_g, tmp_b, p2,
                                        fus_W, fus_b, N);

    // ---- FINAL: out = LN(p0+p1+p2) ----
    k_finE<<<gT, 256, 0, stream>>>(p0, p1, p2, fus_g, fus_be, (float*)d_out, N);
}

// Round 14
// 479.323 us; speedup vs baseline: 1.0390x; 1.0390x over previous
//
#include <hip/hip_runtime.h>

using u32 = unsigned int;
using s64 = long long;

// -------- int width detection --------
__global__ __launch_bounds__(64) void k_detect13(const u32* __restrict__ ei,
                                                 const u32* __restrict__ nt,
                                                 const u32* __restrict__ tp,
                                                 u32* __restrict__ flags) {
    if (blockIdx.x != 0 || threadIdx.x != 0) return;
    bool e64 = true, n64 = true, t64 = true;
    for (int k = 0; k < 64; ++k) {
        if (ei[2 * k + 1] != 0u) e64 = false;
        if (nt[2 * k + 1] != 0u) n64 = false;
        if (tp[2 * k + 1] != 0u) t64 = false;
    }
    flags[0] = e64 ? 1u : 0u;
    flags[1] = n64 ? 1u : 0u;
    flags[2] = t64 ? 1u : 0u;
}

__global__ __launch_bounds__(256) void k_cvt13(const void* __restrict__ src,
                                               int* __restrict__ dst, long long n,
                                               const u32* __restrict__ flags, int fidx) {
    long long i = (long long)blockIdx.x * 256 + threadIdx.x;
    if (i >= n) return;
    dst[i] = flags[fidx] ? (int)((const s64*)src)[i] : ((const int*)src)[i];
}

__global__ __launch_bounds__(256) void kz_i(int* __restrict__ p, int n) {
    int i = blockIdx.x * 256 + threadIdx.x;
    if (i < n) p[i] = 0;
}

// ---------------- counting sort of edges by col ----------------
__global__ __launch_bounds__(256) void k_hist(const int* __restrict__ ei, int E,
                                              int* __restrict__ cnt) {
    int e = blockIdx.x * 256 + threadIdx.x;
    if (e < E) atomicAdd(&cnt[ei[E + e]], 1);
}

__global__ __launch_bounds__(1024) void k_scan(const int* __restrict__ cnt,
                                               int* __restrict__ offA, int N) {
    __shared__ int part[1024];
    int t = threadIdx.x;
    int C = (N + 1023) >> 10;
    int beg = t * C, end = beg + C; if (end > N) end = N;
    int s = 0;
    for (int k = beg; k < end; ++k) s += cnt[k];
    part[t] = s; __syncthreads();
    for (int o = 1; o < 1024; o <<= 1) {
        int v = (t >= o) ? part[t - o] : 0;
        __syncthreads();
        part[t] += v;
        __syncthreads();
    }
    int base = (t == 0) ? 0 : part[t - 1];
    for (int k = beg; k < end; ++k) { offA[k] = base; base += cnt[k]; }
    if (t == 1023) offA[N] = part[1023];
}

__global__ __launch_bounds__(256) void k_scatter(const int* __restrict__ ei, int E,
                                                 const int* __restrict__ offA,
                                                 int* __restrict__ cur,
                                                 int* __restrict__ srow) {
    int e = blockIdx.x * 256 + threadIdx.x;
    if (e >= E) return;
    int col = ei[E + e];
    int p = offA[col] + atomicAdd(&cur[col], 1);
    srow[p] = ei[e];
}

// ---------------- counting sort of nodes by type ----------------
__global__ __launch_bounds__(256) void k_thist(const int* __restrict__ nt, int N,
                                               int* __restrict__ tcnt) {
    __shared__ int lc[6];
    if (threadIdx.x < 6) lc[threadIdx.x] = 0;
    __syncthreads();
    int i = blockIdx.x * 256 + threadIdx.x;
    if (i < N) {
        int t = nt[i]; t = (t < 0 || t > 5) ? 0 : t;
        atomicAdd(&lc[t], 1);
    }
    __syncthreads();
    if (threadIdx.x < 6 && lc[threadIdx.x] > 0) atomicAdd(&tcnt[threadIdx.x], lc[threadIdx.x]);
}

__global__ __launch_bounds__(64) void k_tscan(const int* __restrict__ tcnt,
                                              int* __restrict__ toff) {
    if (threadIdx.x != 0 || blockIdx.x != 0) return;
    int s = 0;
    for (int t = 0; t < 6; ++t) { toff[t] = s; s += tcnt[t]; }
    toff[6] = s;
}

__global__ __launch_bounds__(256) void k_tscatter(const int* __restrict__ nt, int N,
                                                  const int* __restrict__ toff,
                                                  int* __restrict__ tcur,
                                                  int* __restrict__ perm) {
    __shared__ int lc[6], gb[6];
    if (threadIdx.x < 6) lc[threadIdx.x] = 0;
    __syncthreads();
    int i = blockIdx.x * 256 + threadIdx.x;
    int t = 0, lr = 0;
    if (i < N) {
        t = nt[i]; t = (t < 0 || t > 5) ? 0 : t;
        lr = atomicAdd(&lc[t], 1);
    }
    __syncthreads();
    if (threadIdx.x < 6 && lc[threadIdx.x] > 0)
        gb[threadIdx.x] = atomicAdd(&tcur[threadIdx.x], lc[threadIdx.x]);
    __syncthreads();
    if (i < N) perm[toff[t] + gb[t] + lr] = i;
}

__device__ __forceinline__ float2 ld2(const float* p) { return *(const float2*)p; }
__device__ __forceinline__ void st2(float* p, float2 v) { *(float2*)p = v; }
__device__ __forceinline__ float4 ld4(const float* p) { return *(const float4*)p; }
__device__ __forceinline__ void st4(float* p, float4 v) { *(float4*)p = v; }
__device__ __forceinline__ void fma4(float4& a, float s, float4 w) {
    a.x = fmaf(s, w.x, a.x); a.y = fmaf(s, w.y, a.y);
    a.z = fmaf(s, w.z, a.z); a.w = fmaf(s, w.w, a.w);
}

__device__ __forceinline__ float redrow(float s) {
#pragma unroll
    for (int o = 1; o < 32; o <<= 1) s += __shfl_xor(s, o);
    return s;
}

// ======================= staged matmul (R7-proven; unroll-2 inner) =======================
// xs 16KB + wl 32KB = 48KB -> 3 blocks/CU.

__device__ __forceinline__ void stage_half(float* wl, const float* __restrict__ Wg,
                                           int half) {
    int t = threadIdx.x;
    const float* src = Wg + half * 8192;
#pragma unroll
    for (int i = 0; i < 8; ++i) {
        int idx = (t + i * 256) * 4;
        st4(wl + idx, ld4(src + idx));
    }
}

__device__ __forceinline__ void mm_half(float4 (&acc)[4], const float* xs,
                                        const float* wl, int tn, int tc, int k4base) {
#pragma unroll 2
    for (int k4 = 0; k4 < 16; ++k4) {
        int r = k4 * 4;
        float4 w0 = ld4(wl + (r + 0) * 128 + tc * 4);
        float4 w1 = ld4(wl + (r + 1) * 128 + tc * 4);
        float4 w2 = ld4(wl + (r + 2) * 128 + tc * 4);
        float4 w3 = ld4(wl + (r + 3) * 128 + tc * 4);
#pragma unroll
        for (int j = 0; j < 4; ++j) {
            float4 xv = ld4(xs + (tn * 4 + j) * 128 + (k4base + k4) * 4);
            fma4(acc[j], xv.x, w0); fma4(acc[j], xv.y, w1);
            fma4(acc[j], xv.z, w2); fma4(acc[j], xv.w, w3);
        }
    }
}

__device__ __forceinline__ void mmS(float4 (&acc)[4], const float* xs, float* wl,
                                    const float* __restrict__ Wg, int tn, int tc) {
    __syncthreads();
    stage_half(wl, Wg, 0);
    __syncthreads();
    mm_half(acc, xs, wl, tn, tc, 0);
    __syncthreads();
    stage_half(wl, Wg, 1);
    __syncthreads();
    mm_half(acc, xs, wl, tn, tc, 16);
}

__device__ __forceinline__ float4 lnrow(float4 v, const float* g, const float* b, int tc) {
    float m = redrow(v.x + v.y + v.z + v.w) * 0.0078125f;
    float4 d = make_float4(v.x - m, v.y - m, v.z - m, v.w - m);
    float var = redrow(d.x * d.x + d.y * d.y + d.z * d.z + d.w * d.w) * 0.0078125f;
    float r = rsqrtf(var + 1e-5f);
    float4 gg = ld4(g + tc * 4), bb = ld4(b + tc * 4);
    return make_float4(d.x * r * gg.x + bb.x, d.y * r * gg.y + bb.y,
                       d.z * r * gg.z + bb.z, d.w * r * gg.w + bb.w);
}

__device__ __forceinline__ void stage32(float* xs, const float* src, int i0, int N) {
    int t = threadIdx.x;
#pragma unroll
    for (int ii = 0; ii < 4; ++ii) {
        int idx = t + ii * 256;
        int r = idx >> 5, c = idx & 31;
        int node = i0 + r; if (node >= N) node = N - 1;
        st4(xs + r * 128 + c * 4, ld4(src + (size_t)node * 128 + c * 4));
    }
}

__device__ __forceinline__ void xstore(float* xs, const float4 (&v)[4], int tn, int tc) {
#pragma unroll
    for (int j = 0; j < 4; ++j) st4(xs + (tn * 4 + j) * 128 + tc * 4, v[j]);
}

// ============ MEGA1: qkv | hgcn+pre_gcn | pre_tmp (role = blockIdx%3) ============
__global__ __launch_bounds__(256) void k_mega1(
        const float* __restrict__ x,
        const float* __restrict__ Wq, const float* __restrict__ Wk,
        const float* __restrict__ Wv, float* __restrict__ big,
        const int* __restrict__ nt, const int* __restrict__ perm,
        const float* __restrict__ Wt, const float* __restrict__ bt,
        float* __restrict__ h_gcn,
        const float* __restrict__ mW1, const float* __restrict__ mb1,
        float* __restrict__ Pa_g, float* __restrict__ Pb_g,
        const float* __restrict__ emb, const int* __restrict__ tpos,
        const float* __restrict__ tW1, const float* __restrict__ tb1,
        float* __restrict__ Pa_t, float* __restrict__ Pb_t,
        int N) {
    __shared__ float xs[32 * 128];
    __shared__ float wl[64 * 128];
    int role = blockIdx.x % 3;
    int bid = blockIdx.x / 3;
    int t = threadIdx.x, tn = t >> 5, tc = t & 31;
    int i0 = bid * 32;

    if (role == 0) {
        stage32(xs, x, i0, N);
        float4 acc[4];
        const float* Ws[3] = {Wq, Wk, Wv};
#pragma unroll
        for (int m = 0; m < 3; ++m) {
#pragma unroll
            for (int j = 0; j < 4; ++j) acc[j] = make_float4(0.f, 0.f, 0.f, 0.f);
            mmS(acc, xs, wl, Ws[m], tn, tc);
#pragma unroll
            for (int j = 0; j < 4; ++j) {
                int node = i0 + tn * 4 + j;
                if (node < N) st4(big + (size_t)node * 384 + m * 128 + tc * 4, acc[j]);
            }
        }
    } else if (role == 1) {
        // hgcn + pre_gcn chained
#pragma unroll
        for (int ii = 0; ii < 4; ++ii) {
            int idx = t + ii * 256;
            int r = idx >> 5, c = idx & 31;
            int q = i0 + r; if (q >= N) q = N - 1;
            int node = perm[q];
            st4(xs + r * 128 + c * 4, ld4(x + (size_t)node * 128 + c * 4));
        }
        int qa = i0; if (qa >= N) qa = N - 1;
        int qb = i0 + 31; if (qb >= N) qb = N - 1;
        int t0 = nt[perm[qa]]; t0 = (t0 < 0 || t0 > 5) ? 0 : t0;
        int t1 = nt[perm[qb]]; t1 = (t1 < 0 || t1 > 5) ? 0 : t1;
        float4 acc[4];
        if (t0 == t1) {
#pragma unroll
            for (int j = 0; j < 4; ++j) acc[j] = ld4(bt + t0 * 128 + tc * 4);
            mmS(acc, xs, wl, Wt + (size_t)t0 * 16384, tn, tc);
        } else {
            __syncthreads();
#pragma unroll
            for (int j = 0; j < 4; ++j) {
                int q = i0 + tn * 4 + j; if (q >= N) q = N - 1;
                int tt = nt[perm[q]]; tt = (tt < 0 || tt > 5) ? 0 : tt;
                const float* W = Wt + (size_t)tt * 16384;
                float4 a = ld4(bt + tt * 128 + tc * 4);
#pragma unroll 2
                for (int k4 = 0; k4 < 32; ++k4) {
                    float4 xv = ld4(xs + (tn * 4 + j) * 128 + k4 * 4);
                    float4 w0 = ld4(W + (size_t)(k4 * 4 + 0) * 128 + tc * 4);
                    float4 w1 = ld4(W + (size_t)(k4 * 4 + 1) * 128 + tc * 4);
                    float4 w2 = ld4(W + (size_t)(k4 * 4 + 2) * 128 + tc * 4);
                    float4 w3 = ld4(W + (size_t)(k4 * 4 + 3) * 128 + tc * 4);
                    fma4(a, xv.x, w0); fma4(a, xv.y, w1);
                    fma4(a, xv.z, w2); fma4(a, xv.w, w3);
                }
                acc[j] = a;
            }
        }
#pragma unroll
        for (int j = 0; j < 4; ++j) {
            int q = i0 + tn * 4 + j;
            if (q < N) st4(h_gcn + (size_t)perm[q] * 128 + tc * 4, acc[j]);
        }
        __syncthreads();
        xstore(xs, acc, tn, tc);
        float4 pa[4];
#pragma unroll
        for (int j = 0; j < 4; ++j) pa[j] = make_float4(0.f, 0.f, 0.f, 0.f);
        mmS(pa, xs, wl, mW1, tn, tc);
#pragma unroll
        for (int j = 0; j < 4; ++j) {
            int q = i0 + tn * 4 + j;
            if (q < N) st4(Pa_g + (size_t)perm[q] * 128 + tc * 4, pa[j]);
        }
        float4 b14 = ld4(mb1 + tc * 4);
        float4 pb[4];
#pragma unroll
        for (int j = 0; j < 4; ++j) pb[j] = b14;
        mmS(pb, xs, wl, mW1 + (size_t)128 * 128, tn, tc);
#pragma unroll
        for (int j = 0; j < 4; ++j) {
            int q = i0 + tn * 4 + j;
            if (q < N) st4(Pb_g + (size_t)perm[q] * 128 + tc * 4, pb[j]);
        }
    } else {
        // pre_tmp (h = x + emb inline)
#pragma unroll
        for (int ii = 0; ii < 4; ++ii) {
            int idx = t + ii * 256;
            int r = idx >> 5, c = idx & 31;
            int node = i0 + r; if (node >= N) node = N - 1;
            float4 v = ld4(x + (size_t)node * 128 + c * 4);
            int tp = tpos[node]; tp = tp < 0 ? 0 : (tp > 49 ? 49 : tp);
            float4 e = ld4(emb + tp * 128 + c * 4);
            v.x += e.x; v.y += e.y; v.z += e.z; v.w += e.w;
            st4(xs + r * 128 + c * 4, v);
        }
        float4 acc[4];
#pragma unroll
        for (int j = 0; j < 4; ++j) acc[j] = make_float4(0.f, 0.f, 0.f, 0.f);
        mmS(acc, xs, wl, tW1, tn, tc);
#pragma unroll
        for (int j = 0; j < 4; ++j) {
            int node = i0 + tn * 4 + j;
            if (node < N) st4(Pa_t + (size_t)node * 128 + tc * 4, acc[j]);
        }
        float4 b14 = ld4(tb1 + tc * 4);
#pragma unroll
        for (int j = 0; j < 4; ++j) acc[j] = b14;
        mmS(acc, xs, wl, tW1 + (size_t)128 * 128, tn, tc);
#pragma unroll
        for (int j = 0; j < 4; ++j) {
            int node = i0 + tn * 4 + j;
            if (node < N) st4(Pb_t + (size_t)node * 128 + tc * 4, acc[j]);
        }
    }
}

// rsum body (s aliases Pb: pb read before s written)
__device__ __forceinline__ void rsum_body(const float* __restrict__ Pa,
                                          float* __restrict__ Pb,
                                          const int* __restrict__ srow,
                                          const int* __restrict__ offA, int N, int cb) {
    int l = threadIdx.x & 63;
    int col = cb * 4 + (threadIdx.x >> 6);
    if (col >= N) return;
    float2 pb = ld2(Pb + (size_t)col * 128 + 2 * l);
    float ax = 0.f, ay = 0.f;
    int p = offA[col], pe = offA[col + 1];
    for (; p + 4 <= pe; p += 4) {
        int r0 = srow[p], r1 = srow[p + 1], r2 = srow[p + 2], r3 = srow[p + 3];
        float2 a0 = ld2(Pa + (size_t)r0 * 128 + 2 * l);
        float2 a1 = ld2(Pa + (size_t)r1 * 128 + 2 * l);
        float2 a2 = ld2(Pa + (size_t)r2 * 128 + 2 * l);
        float2 a3 = ld2(Pa + (size_t)r3 * 128 + 2 * l);
        ax += fmaxf(a0.x + pb.x, 0.f) + fmaxf(a1.x + pb.x, 0.f)
            + fmaxf(a2.x + pb.x, 0.f) + fmaxf(a3.x + pb.x, 0.f);
        ay += fmaxf(a0.y + pb.y, 0.f) + fmaxf(a1.y + pb.y, 0.f)
            + fmaxf(a2.y + pb.y, 0.f) + fmaxf(a3.y + pb.y, 0.f);
    }
    for (; p < pe; ++p) {
        int r = srow[p];
        float2 a = ld2(Pa + (size_t)r * 128 + 2 * l);
        ax += fmaxf(a.x + pb.x, 0.f);
        ay += fmaxf(a.y + pb.y, 0.f);
    }
    st2(Pb + (size_t)col * 128 + 2 * l, make_float2(ax, ay));
}

// ============ MEGA2: fused GAT softmax+WV | rsum_gcn | rsum_tmp ============
__global__ __launch_bounds__(256) void k_mega2(
        const float* __restrict__ big,
        const float* __restrict__ Pa_g, float* __restrict__ Pb_g,
        const float* __restrict__ Pa_t, float* __restrict__ Pb_t,
        const int* __restrict__ srow, const int* __restrict__ offA,
        float* __restrict__ agg, int N) {
    int role = blockIdx.x % 3;
    int cb = blockIdx.x / 3;
    if (role == 1) { rsum_body(Pa_g, Pb_g, srow, offA, N, cb); return; }
    if (role == 2) { rsum_body(Pa_t, Pb_t, srow, offA, N, cb); return; }
    // ---- fused GAT ----
    int l = threadIdx.x & 63;
    int col = cb * 4 + (threadIdx.x >> 6);
    if (col >= N) return;
    float2 kc = ld2(big + (size_t)col * 384 + 128 + 2 * l);
    float ax = 0.f, ay = 0.f, den = 0.f;
    int p = offA[col], pe = offA[col + 1];
    for (; p + 2 <= pe; p += 2) {
        int r0 = srow[p], r1 = srow[p + 1];
        float2 q0 = ld2(big + (size_t)r0 * 384 + 2 * l);
        float2 v0 = ld2(big + (size_t)r0 * 384 + 256 + 2 * l);
        float2 q1 = ld2(big + (size_t)r1 * 384 + 2 * l);
        float2 v1 = ld2(big + (size_t)r1 * 384 + 256 + 2 * l);
        float pt0 = q0.x * kc.x + q0.y * kc.y;
        float pt1 = q1.x * kc.x + q1.y * kc.y;
        pt0 += __shfl_xor(pt0, 1); pt1 += __shfl_xor(pt1, 1);
        pt0 += __shfl_xor(pt0, 2); pt1 += __shfl_xor(pt1, 2);
        pt0 += __shfl_xor(pt0, 4); pt1 += __shfl_xor(pt1, 4);
        float s0 = pt0 * 0.25f; s0 = s0 > 0.f ? s0 : 0.2f * s0;
        float s1 = pt1 * 0.25f; s1 = s1 > 0.f ? s1 : 0.2f * s1;
        float e0 = expf(s0), e1 = expf(s1);
        den += e0 + e1;
        ax = fmaf(e0, v0.x, ax); ay = fmaf(e0, v0.y, ay);
        ax = fmaf(e1, v1.x, ax); ay = fmaf(e1, v1.y, ay);
    }
    for (; p < pe; ++p) {
        int r = srow[p];
        float2 q0 = ld2(big + (size_t)r * 384 + 2 * l);
        float2 v0 = ld2(big + (size_t)r * 384 + 256 + 2 * l);
        float pt = q0.x * kc.x + q0.y * kc.y;
        pt += __shfl_xor(pt, 1);
        pt += __shfl_xor(pt, 2);
        pt += __shfl_xor(pt, 4);
        float s = pt * 0.25f; s = s > 0.f ? s : 0.2f * s;
        float e = expf(s);
        den += e;
        ax = fmaf(e, v0.x, ax); ay = fmaf(e, v0.y, ay);
    }
    float ism = den != 0.f ? 1.f / den : 0.f;
    st2(agg + (size_t)col * 128 + 2 * l, make_float2(ax * ism, ay * ism));
}

// ============ MEGA3: epilogues + fusW partials (role = blockIdx%3) ============
__global__ __launch_bounds__(256) void k_mega3(
        const float* __restrict__ x,
        const float* __restrict__ agg,
        const float* __restrict__ gWo, const float* __restrict__ gbo,
        const float* __restrict__ gg, const float* __restrict__ gb,
        float* __restrict__ p0,
        const float* __restrict__ h_gcn, const float* __restrict__ s_gcn,
        const int* __restrict__ offA,
        const float* __restrict__ W2, const float* __restrict__ b2,
        const float* __restrict__ aW1, const float* __restrict__ ab1,
        const float* __restrict__ aW2, const float* __restrict__ ab2,
        const float* __restrict__ cWo, const float* __restrict__ cbo,
        const float* __restrict__ cg, const float* __restrict__ cb,
        float* __restrict__ p1,
        const float* __restrict__ emb, const int* __restrict__ tpos,
        const float* __restrict__ s_tmp,
        const float* __restrict__ tW2, const float* __restrict__ tb2,
        const float* __restrict__ tWo, const float* __restrict__ tbo,
        const float* __restrict__ tg, const float* __restrict__ tb,
        float* __restrict__ p2,
        const float* __restrict__ fusW, const float* __restrict__ fus_b,
        int N) {
    __shared__ float xs[32 * 128];
    __shared__ float wl[64 * 128];
    int role = blockIdx.x % 3;
    int bid = blockIdx.x / 3;
    int t = threadIdx.x, tn = t >> 5, tc = t & 31;
    int i0 = bid * 32;
    int node[4];
#pragma unroll
    for (int j = 0; j < 4; ++j) {
        node[j] = i0 + tn * 4 + j; if (node[j] >= N) node[j] = N - 1;
    }
    float4 o[4];

    if (role == 0) {
        // ep_gat: o = LN(agg@Wo + bo + x); p0 = fus_b + o@fusW0
        stage32(xs, agg, i0, N);
        float4 acc[4];
        float4 bo4 = ld4(gbo + tc * 4);
#pragma unroll
        for (int j = 0; j < 4; ++j) acc[j] = bo4;
        mmS(acc, xs, wl, gWo, tn, tc);
#pragma unroll
        for (int j = 0; j < 4; ++j) {
            float4 xr = ld4(x + (size_t)node[j] * 128 + tc * 4);
            float4 v = make_float4(acc[j].x + xr.x, acc[j].y + xr.y,
                                   acc[j].z + xr.z, acc[j].w + xr.w);
            o[j] = lnrow(v, gg, gb, tc);
        }
        __syncthreads();
        xstore(xs, o, tn, tc);
        float4 fb4 = ld4(fus_b + tc * 4);
#pragma unroll
        for (int j = 0; j < 4; ++j) acc[j] = fb4;
        mmS(acc, xs, wl, fusW, tn, tc);
#pragma unroll
        for (int j = 0; j < 4; ++j) {
            int q = i0 + tn * 4 + j;
            if (q < N) st4(p0 + (size_t)q * 128 + tc * 4, acc[j]);
        }
    } else if (role == 1) {
        // ep_gcn
        stage32(xs, s_gcn, i0, N);
        float4 acc[4];
        float4 b24 = ld4(b2 + tc * 4);
#pragma unroll
        for (int j = 0; j < 4; ++j) {
            float deg = (float)(offA[node[j] + 1] - offA[node[j]]);
            acc[j] = make_float4(deg * b24.x, deg * b24.y, deg * b24.z, deg * b24.w);
        }
        mmS(acc, xs, wl, W2, tn, tc);
        __syncthreads();
        xstore(xs, acc, tn, tc);
        float4 u[4];
        float4 a14 = ld4(ab1 + tc * 4);
#pragma unroll
        for (int j = 0; j < 4; ++j) u[j] = a14;
        mmS(u, xs, wl, aW1, tn, tc);
#pragma unroll
        for (int j = 0; j < 4; ++j) {
            u[j].x = fmaxf(u[j].x, 0.f); u[j].y = fmaxf(u[j].y, 0.f);
            u[j].z = fmaxf(u[j].z, 0.f); u[j].w = fmaxf(u[j].w, 0.f);
        }
        __syncthreads();
        xstore(xs, u, tn, tc);
        float4 z3[4];
        float4 a24 = ld4(ab2 + tc * 4);
#pragma unroll
        for (int j = 0; j < 4; ++j) z3[j] = a24;
        mmS(z3, xs, wl, aW2, tn, tc);
#pragma unroll
        for (int j = 0; j < 4; ++j) {
            float4 hg = ld4(h_gcn + (size_t)node[j] * 128 + tc * 4);
            z3[j].x += hg.x; z3[j].y += hg.y; z3[j].z += hg.z; z3[j].w += hg.w;
        }
        __syncthreads();
        xstore(xs, z3, tn, tc);
        float4 d[4];
        float4 bo4 = ld4(cbo + tc * 4);
#pragma unroll
        for (int j = 0; j < 4; ++j) d[j] = bo4;
        mmS(d, xs, wl, cWo, tn, tc);
#pragma unroll
        for (int j = 0; j < 4; ++j) {
            float4 xr = ld4(x + (size_t)node[j] * 128 + tc * 4);
            float4 v = make_float4(d[j].x + xr.x, d[j].y + xr.y,
                                   d[j].z + xr.z, d[j].w + xr.w);
            o[j] = lnrow(v, cg, cb, tc);
        }
        __syncthreads();
        xstore(xs, o, tn, tc);
#pragma unroll
        for (int j = 0; j < 4; ++j) d[j] = make_float4(0.f, 0.f, 0.f, 0.f);
        mmS(d, xs, wl, fusW + (size_t)128 * 128, tn, tc);
#pragma unroll
        for (int j = 0; j < 4; ++j) {
            int q = i0 + tn * 4 + j;
            if (q < N) st4(p1 + (size_t)q * 128 + tc * 4, d[j]);
        }
    } else {
        // ep_tmp
        stage32(xs, s_tmp, i0, N);
        float4 acc[4];
        float4 b24 = ld4(tb2 + tc * 4);
#pragma unroll
        for (int j = 0; j < 4; ++j) {
            float deg = (float)(offA[node[j] + 1] - offA[node[j]]);
            acc[j] = make_float4(deg * b24.x, deg * b24.y, deg * b24.z, deg * b24.w);
        }
        mmS(acc, xs, wl, tW2, tn, tc);
#pragma unroll
        for (int j = 0; j < 4; ++j) {
            int tp = tpos[node[j]]; tp = tp < 0 ? 0 : (tp > 49 ? 49 : tp);
            float4 xr = ld4(x + (size_t)node[j] * 128 + tc * 4);
            float4 e = ld4(emb + tp * 128 + tc * 4);
            acc[j].x += xr.x + e.x; acc[j].y += xr.y + e.y;
            acc[j].z += xr.z + e.z; acc[j].w += xr.w + e.w;
        }
        __syncthreads();
        xstore(xs, acc, tn, tc);
        float4 d[4];
        float4 bo4 = ld4(tbo + tc * 4);
#pragma unroll
        for (int j = 0; j < 4; ++j) d[j] = bo4;
        mmS(d, xs, wl, tWo, tn, tc);
#pragma unroll
        for (int j = 0; j < 4; ++j) o[j] = lnrow(d[j], tg, tb, tc);
        __syncthreads();
        xstore(xs, o, tn, tc);
#pragma unroll
        for (int j = 0; j < 4; ++j) d[j] = make_float4(0.f, 0.f, 0.f, 0.f);
        mmS(d, xs, wl, fusW + (size_t)256 * 128, tn, tc);
#pragma unroll
        for (int j = 0; j < 4; ++j) {
            int q = i0 + tn * 4 + j;
            if (q < N) st4(p2 + (size_t)q * 128 + tc * 4, d[j]);
        }
    }
}

// ============ FINAL: out = LN(p0 + p1 + p2) (elementwise rows) ============
__global__ __launch_bounds__(256) void k_finE(
        const float* __restrict__ p0, const float* __restrict__ p1,
        const float* __restrict__ p2,
        const float* __restrict__ fg, const float* __restrict__ fbe,
        float* __restrict__ out, int N) {
    int t = threadIdx.x, tn = t >> 5, tc = t & 31;
    int i0 = blockIdx.x * 32;
#pragma unroll
    for (int j = 0; j < 4; ++j) {
        int node = i0 + tn * 4 + j;
        int nc = node < N ? node : N - 1;
        float4 a = ld4(p0 + (size_t)nc * 128 + tc * 4);
        float4 b = ld4(p1 + (size_t)nc * 128 + tc * 4);
        float4 c = ld4(p2 + (size_t)nc * 128 + tc * 4);
        float4 v = make_float4(a.x + b.x + c.x, a.y + b.y + c.y,
                               a.z + b.z + c.z, a.w + b.w + c.w);
        float4 o = lnrow(v, fg, fbe, tc);
        if (node < N) st4(out + (size_t)node * 128 + tc * 4, o);
    }
}

extern "C" void kernel_launch(void* const* d_in, const int* in_sizes, int n_in, void* d_out,
                              int out_size, void* d_ws, size_t ws_size, hipStream_t stream) {
    (void)n_in; (void)out_size; (void)ws_size;
    const float* x = (const float*)d_in[0];
    const float* gat_Wq = (const float*)d_in[4];
    const float* gat_Wk = (const float*)d_in[5];
    const float* gat_Wv = (const float*)d_in[6];
    const float* gat_Wo = (const float*)d_in[7];
    const float* gat_bo = (const float*)d_in[8];
    const float* gat_g = (const float*)d_in[9];
    const float* gat_b = (const float*)d_in[10];
    const float* gcn_Wt = (const float*)d_in[11];
    const float* gcn_bt = (const float*)d_in[12];
    const float* gcn_mW1 = (const float*)d_in[13];
    const float* gcn_mb1 = (const float*)d_in[14];
    const float* gcn_mW2 = (const float*)d_in[15];
    const float* gcn_mb2 = (const float*)d_in[16];
    const float* gcn_aW1 = (const float*)d_in[17];
    const float* gcn_ab1 = (const float*)d_in[18];
    const float* gcn_aW2 = (const float*)d_in[19];
    const float* gcn_ab2 = (const float*)d_in[20];
    const float* gcn_Wo = (const float*)d_in[21];
    const float* gcn_bo = (const float*)d_in[22];
    const float* gcn_g = (const float*)d_in[23];
    const float* gcn_b = (const float*)d_in[24];
    const float* tmp_emb = (const float*)d_in[25];
    const float* tmp_W1 = (const float*)d_in[26];
    const float* tmp_b1 = (const float*)d_in[27];
    const float* tmp_W2 = (const float*)d_in[28];
    const float* tmp_b2 = (const float*)d_in[29];
    const float* tmp_Wo = (const float*)d_in[30];
    const float* tmp_bo = (const float*)d_in[31];
    const float* tmp_g = (const float*)d_in[32];
    const float* tmp_b = (const float*)d_in[33];
    const float* fus_W = (const float*)d_in[34];
    const float* fus_b = (const float*)d_in[35];
    const float* fus_g = (const float*)d_in[36];
    const float* fus_be = (const float*)d_in[37];

    int N = in_sizes[0] / 128;
    int E = in_sizes[1] / 2;

    // ---- workspace layout ----
    float* ws = (float*)d_ws;
    float* big = ws;                          // [0,384N): QKV; p0/p1/p2 after mega3
    float* p0 = ws;
    float* p1 = ws + (size_t)128 * N;
    float* p2 = ws + (size_t)256 * N;
    float* h_gcn = ws + (size_t)384 * N;      // [384N,512N)
    float* Pa_g = ws + (size_t)512 * N;       // [512N,640N)
    float* Pb_g = ws + (size_t)640 * N;       // s_gcn in-place
    float* Pa_t = ws + (size_t)768 * N;       // [768N,896N)
    float* Pb_t = ws + (size_t)896 * N;       // s_tmp in-place
    float* agg = ws + (size_t)1024 * N;       // [1024N,1152N)
    u32* flags = (u32*)(ws + (size_t)1152 * N);
    int* ei32 = (int*)(flags + 16);
    int* nt32 = ei32 + (size_t)2 * E;
    int* tp32 = nt32 + N;
    int* offA = tp32 + N;                     // N+1
    int* cur = offA + (N + 1);                // N
    int* srow = cur + N;                      // E
    int* tcnt = srow + E;                     // 6
    int* toff = tcnt + 6;                     // 7
    int* tcur = toff + 7;                     // 6
    int* perm = cur;                          // alias after col-scatter

    // ---- index canonicalization ----
    k_detect13<<<1, 64, 0, stream>>>((const u32*)d_in[1], (const u32*)d_in[2],
                                     (const u32*)d_in[3], flags);
    long long nEI = (long long)2 * E;
    k_cvt13<<<(int)((nEI + 255) / 256), 256, 0, stream>>>(d_in[1], ei32, nEI, flags, 0);
    k_cvt13<<<(N + 255) / 256, 256, 0, stream>>>(d_in[2], nt32, N, flags, 1);
    k_cvt13<<<(N + 255) / 256, 256, 0, stream>>>(d_in[3], tp32, N, flags, 2);

    int gE = (E + 255) / 256;
    int gN = (N + 255) / 256;
    int gT = (N + 31) / 32;
    int gC = (N + 3) / 4;

    // ---- counting sort of edges by col ----
    kz_i<<<gN, 256, 0, stream>>>(cur, N);
    k_hist<<<gE, 256, 0, stream>>>(ei32, E, cur);
    k_scan<<<1, 1024, 0, stream>>>(cur, offA, N);
    kz_i<<<gN, 256, 0, stream>>>(cur, N);
    k_scatter<<<gE, 256, 0, stream>>>(ei32, E, offA, cur, srow);

    // ---- counting sort of nodes by type ----
    kz_i<<<1, 32, 0, stream>>>(tcnt, 19);
    k_thist<<<gN, 256, 0, stream>>>(nt32, N, tcnt);
    k_tscan<<<1, 64, 0, stream>>>(tcnt, toff);
    k_tscatter<<<gN, 256, 0, stream>>>(nt32, N, toff, tcur, perm);

    // ---- MEGA1: qkv | hgcn+pre_gcn | pre_tmp ----
    k_mega1<<<3 * gT, 256, 0, stream>>>(x, gat_Wq, gat_Wk, gat_Wv, big,
                                        nt32, perm, gcn_Wt, gcn_bt, h_gcn,
                                        gcn_mW1, gcn_mb1, Pa_g, Pb_g,
                                        tmp_emb, tp32, tmp_W1, tmp_b1, Pa_t, Pb_t, N);

    // ---- MEGA2: fused GAT | rsum_gcn | rsum_tmp ----
    k_mega2<<<3 * gC, 256, 0, stream>>>(big, Pa_g, Pb_g, Pa_t, Pb_t,
                                        srow, offA, agg, N);

    // ---- MEGA3: epilogues + fusW partials ----
    k_mega3<<<3 * gT, 256, 0, stream>>>(x, agg, gat_Wo, gat_bo, gat_g, gat_b, p0,
                                        h_gcn, Pb_g, offA, gcn_mW2, gcn_mb2,
                                        gcn_aW1, gcn_ab1, gcn_aW2, gcn_ab2,
                                        gcn_Wo, gcn_bo, gcn_g, gcn_b, p1,
                                        tmp_emb, tp32, Pb_t, tmp_W2, tmp_b2,
                                        tmp_Wo, tmp_bo, tmp_g, tmp_b, p2,
                                        fus_W, fus_b, N);

    // ---- FINAL: out = LN(p0+p1+p2) ----
    k_finE<<<gT, 256, 0, stream>>>(p0, p1, p2, fus_g, fus_be, (float*)d_out, N);
}